// Round 1
// baseline (868.022 us; speedup 1.0000x reference)
//
#include <hip/hip_runtime.h>
#include <math.h>

#define T_TOK 4096
#define DM 1024
#define DF 4096
#define NE 8

#define BM 128
#define BN 128
#define BK 32
#define LSTR 40   // LDS row stride in bf16 elems (BK + 8 pad)

typedef __attribute__((ext_vector_type(8))) short bf16x8;
typedef __attribute__((ext_vector_type(4))) float f32x4;

__device__ __forceinline__ unsigned short f2bf(float f) {
    union { float f; unsigned int u; } v; v.f = f;
    unsigned int r = v.u + 0x7FFFu + ((v.u >> 16) & 1u);
    return (unsigned short)(r >> 16);
}
__device__ __forceinline__ unsigned int pk(float a, float b) {
    return (unsigned int)f2bf(a) | ((unsigned int)f2bf(b) << 16);
}
__device__ __forceinline__ uint4 pack8(float4 a, float4 b) {
    union { uint4 u4; unsigned short s[8]; } r;
    r.s[0]=f2bf(a.x); r.s[1]=f2bf(a.y); r.s[2]=f2bf(a.z); r.s[3]=f2bf(a.w);
    r.s[4]=f2bf(b.x); r.s[5]=f2bf(b.y); r.s[6]=f2bf(b.z); r.s[7]=f2bf(b.w);
    return r.u4;
}

// ---------------- router: 1 wave per token ----------------
__global__ __launch_bounds__(256) void k_router(
    const float* __restrict__ x, const float* __restrict__ noise,
    const float* __restrict__ Wg, const float* __restrict__ bg,
    const float* __restrict__ Wn, const float* __restrict__ bn,
    int* __restrict__ counts, int* __restrict__ slots, float* __restrict__ gates)
{
    const int lane = threadIdx.x & 63;
    const int wave = threadIdx.x >> 6;
    const int t = blockIdx.x * 4 + wave;
    const float* xr = x + (size_t)t * DM + lane * 16;

    float accg[8], accn[8];
    #pragma unroll
    for (int i = 0; i < 8; ++i) { accg[i] = 0.f; accn[i] = 0.f; }

    #pragma unroll
    for (int dd = 0; dd < 16; ++dd) {
        float xv = xr[dd];
        int d = lane * 16 + dd;
        float4 g0 = *(const float4*)(Wg + d * 8);
        float4 g1 = *(const float4*)(Wg + d * 8 + 4);
        float4 n0 = *(const float4*)(Wn + d * 8);
        float4 n1 = *(const float4*)(Wn + d * 8 + 4);
        accg[0] += xv * g0.x; accg[1] += xv * g0.y; accg[2] += xv * g0.z; accg[3] += xv * g0.w;
        accg[4] += xv * g1.x; accg[5] += xv * g1.y; accg[6] += xv * g1.z; accg[7] += xv * g1.w;
        accn[0] += xv * n0.x; accn[1] += xv * n0.y; accn[2] += xv * n0.z; accn[3] += xv * n0.w;
        accn[4] += xv * n1.x; accn[5] += xv * n1.y; accn[6] += xv * n1.z; accn[7] += xv * n1.w;
    }
    #pragma unroll
    for (int s = 1; s < 64; s <<= 1) {
        #pragma unroll
        for (int e = 0; e < 8; ++e) {
            accg[e] += __shfl_xor(accg[e], s, 64);
            accn[e] += __shfl_xor(accn[e], s, 64);
        }
    }
    if (lane == 0) {
        float nv[8];
        #pragma unroll
        for (int e = 0; e < 8; ++e) {
            float lg = accg[e] + bg[e];
            float nl = accn[e] + bn[e];
            float sp = (nl > 20.f) ? nl : log1pf(expf(nl));
            nv[e] = lg + noise[(size_t)t * NE + e] * sp;
        }
        int i0 = 0;
        #pragma unroll
        for (int e = 1; e < 8; ++e) if (nv[e] > nv[i0]) i0 = e;
        int i1 = -1;
        #pragma unroll
        for (int e = 0; e < 8; ++e) {
            if (e == i0) continue;
            if (i1 < 0 || nv[e] > nv[i1]) i1 = e;
        }
        float ex = expf(nv[i1] - nv[i0]);     // <= 1
        float g0 = 1.f / (1.f + ex);
        float g1 = ex / (1.f + ex);
        int p0 = atomicAdd(counts + i0, 1);
        slots[i0 * T_TOK + p0] = t * 2;     gates[i0 * T_TOK + p0] = g0;
        int p1 = atomicAdd(counts + i1, 1);
        slots[i1 * T_TOK + p1] = t * 2 + 1; gates[i1 * T_TOK + p1] = g1;
    }
}

// ---------------- fc1: h[slot] = relu(x[tok] @ W1[e] + b1[e]) ----------------
__global__ __launch_bounds__(256) void k_fc1(
    const float* __restrict__ x, const float* __restrict__ W1,
    const float* __restrict__ b1, const int* __restrict__ counts,
    const int* __restrict__ slots, unsigned short* __restrict__ h)
{
    const int e = blockIdx.z;
    const int cnt = counts[e];
    const int mt = blockIdx.y;
    if (mt * BM >= cnt) return;
    const int nb = blockIdx.x * BN;

    __shared__ short As[BM * LSTR];
    __shared__ short Bs[BN * LSTR];
    __shared__ int slot_s[BM];

    const int tid = threadIdx.x;
    if (tid < BM) {
        int gi = mt * BM + tid;
        slot_s[tid] = (gi < cnt) ? slots[e * T_TOK + gi] : -1;
    }
    __syncthreads();

    const int arow = tid >> 1, ahalf = tid & 1;
    const int aslot = slot_s[arow];
    const float* axp = (aslot >= 0) ? (x + (size_t)(aslot >> 1) * DM + ahalf * 16) : x;
    short* awp = As + arow * LSTR + ahalf * 16;

    const int bkp = tid >> 4;             // 0..15 (k-pair)
    const int bn8 = (tid & 15) * 8;       // n offset within tile
    const float* bwp = W1 + (size_t)e * DM * DF + (size_t)(2 * bkp) * DF + nb + bn8;

    const int lane = tid & 63, wv = tid >> 6;
    const int wm = (wv & 1) * 64, wn = (wv >> 1) * 64;
    const int ml = lane & 15, kg = lane >> 4;

    f32x4 acc[4][4];
    #pragma unroll
    for (int mi = 0; mi < 4; ++mi)
        #pragma unroll
        for (int ni = 0; ni < 4; ++ni) acc[mi][ni] = (f32x4){0.f, 0.f, 0.f, 0.f};

    for (int k0 = 0; k0 < DM; k0 += BK) {
        uint4 a0, a1;
        if (aslot >= 0) {
            const float4* p = (const float4*)(axp + k0);
            a0 = pack8(p[0], p[1]);
            a1 = pack8(p[2], p[3]);
        } else {
            a0 = make_uint4(0, 0, 0, 0); a1 = a0;
        }
        const float* q = bwp + (size_t)k0 * DF;
        float4 r0a = ((const float4*)q)[0];
        float4 r0b = ((const float4*)q)[1];
        float4 r1a = ((const float4*)(q + DF))[0];
        float4 r1b = ((const float4*)(q + DF))[1];

        ((uint4*)awp)[0] = a0;
        ((uint4*)awp)[1] = a1;
        unsigned int* bb = (unsigned int*)(Bs + bn8 * LSTR + 2 * bkp);
        bb[0 * (LSTR / 2)] = pk(r0a.x, r1a.x);
        bb[1 * (LSTR / 2)] = pk(r0a.y, r1a.y);
        bb[2 * (LSTR / 2)] = pk(r0a.z, r1a.z);
        bb[3 * (LSTR / 2)] = pk(r0a.w, r1a.w);
        bb[4 * (LSTR / 2)] = pk(r0b.x, r1b.x);
        bb[5 * (LSTR / 2)] = pk(r0b.y, r1b.y);
        bb[6 * (LSTR / 2)] = pk(r0b.z, r1b.z);
        bb[7 * (LSTR / 2)] = pk(r0b.w, r1b.w);
        __syncthreads();

        bf16x8 af[4], bfg[4];
        #pragma unroll
        for (int mi = 0; mi < 4; ++mi)
            af[mi] = *(const bf16x8*)(As + (wm + mi * 16 + ml) * LSTR + kg * 8);
        #pragma unroll
        for (int ni = 0; ni < 4; ++ni)
            bfg[ni] = *(const bf16x8*)(Bs + (wn + ni * 16 + ml) * LSTR + kg * 8);
        #pragma unroll
        for (int mi = 0; mi < 4; ++mi)
            #pragma unroll
            for (int ni = 0; ni < 4; ++ni)
                acc[mi][ni] = __builtin_amdgcn_mfma_f32_16x16x32_bf16(af[mi], bfg[ni], acc[mi][ni], 0, 0, 0);
        __syncthreads();
    }

    float bias[4];
    #pragma unroll
    for (int ni = 0; ni < 4; ++ni)
        bias[ni] = b1[(size_t)e * DF + nb + wn + ni * 16 + ml];

    #pragma unroll
    for (int mi = 0; mi < 4; ++mi) {
        #pragma unroll
        for (int r = 0; r < 4; ++r) {
            int row = wm + mi * 16 + kg * 4 + r;
            int s = slot_s[row];
            if (s < 0) continue;
            unsigned short* hrow = h + (size_t)s * DF + nb;
            #pragma unroll
            for (int ni = 0; ni < 4; ++ni) {
                float v = acc[mi][ni][r] + bias[ni];
                v = fmaxf(v, 0.f);
                hrow[wn + ni * 16 + ml] = f2bf(v);
            }
        }
    }
}

// ---------------- fc2: out[tok] += gate * (h[slot] @ W2[e] + b2[e]) ----------------
__global__ __launch_bounds__(256) void k_fc2(
    const unsigned short* __restrict__ h, const float* __restrict__ W2,
    const float* __restrict__ b2, const int* __restrict__ counts,
    const int* __restrict__ slots, const float* __restrict__ gates,
    float* __restrict__ out)
{
    const int e = blockIdx.z;
    const int cnt = counts[e];
    const int mt = blockIdx.y;
    if (mt * BM >= cnt) return;
    const int nb = blockIdx.x * BN;

    __shared__ short As[BM * LSTR];
    __shared__ short Bs[BN * LSTR];
    __shared__ int slot_s[BM];
    __shared__ float gate_s[BM];

    const int tid = threadIdx.x;
    if (tid < BM) {
        int gi = mt * BM + tid;
        if (gi < cnt) {
            slot_s[tid] = slots[e * T_TOK + gi];
            gate_s[tid] = gates[e * T_TOK + gi];
        } else {
            slot_s[tid] = -1; gate_s[tid] = 0.f;
        }
    }
    __syncthreads();

    const int arow = tid >> 1, ahalf = tid & 1;
    const int aslot = slot_s[arow];
    const unsigned short* ahp = (aslot >= 0) ? (h + (size_t)aslot * DF + ahalf * 16) : h;
    short* awp = As + arow * LSTR + ahalf * 16;

    const int bkp = tid >> 4;
    const int bn8 = (tid & 15) * 8;
    const float* bwp = W2 + (size_t)e * DF * DM + (size_t)(2 * bkp) * DM + nb + bn8;

    const int lane = tid & 63, wv = tid >> 6;
    const int wm = (wv & 1) * 64, wn = (wv >> 1) * 64;
    const int ml = lane & 15, kg = lane >> 4;

    f32x4 acc[4][4];
    #pragma unroll
    for (int mi = 0; mi < 4; ++mi)
        #pragma unroll
        for (int ni = 0; ni < 4; ++ni) acc[mi][ni] = (f32x4){0.f, 0.f, 0.f, 0.f};

    for (int k0 = 0; k0 < DF; k0 += BK) {
        uint4 a0, a1;
        if (aslot >= 0) {
            a0 = ((const uint4*)(ahp + k0))[0];
            a1 = ((const uint4*)(ahp + k0))[1];
        } else {
            a0 = make_uint4(0, 0, 0, 0); a1 = a0;
        }
        const float* q = bwp + (size_t)k0 * DM;
        float4 r0a = ((const float4*)q)[0];
        float4 r0b = ((const float4*)q)[1];
        float4 r1a = ((const float4*)(q + DM))[0];
        float4 r1b = ((const float4*)(q + DM))[1];

        ((uint4*)awp)[0] = a0;
        ((uint4*)awp)[1] = a1;
        unsigned int* bb = (unsigned int*)(Bs + bn8 * LSTR + 2 * bkp);
        bb[0 * (LSTR / 2)] = pk(r0a.x, r1a.x);
        bb[1 * (LSTR / 2)] = pk(r0a.y, r1a.y);
        bb[2 * (LSTR / 2)] = pk(r0a.z, r1a.z);
        bb[3 * (LSTR / 2)] = pk(r0a.w, r1a.w);
        bb[4 * (LSTR / 2)] = pk(r0b.x, r1b.x);
        bb[5 * (LSTR / 2)] = pk(r0b.y, r1b.y);
        bb[6 * (LSTR / 2)] = pk(r0b.z, r1b.z);
        bb[7 * (LSTR / 2)] = pk(r0b.w, r1b.w);
        __syncthreads();

        bf16x8 af[4], bfg[4];
        #pragma unroll
        for (int mi = 0; mi < 4; ++mi)
            af[mi] = *(const bf16x8*)(As + (wm + mi * 16 + ml) * LSTR + kg * 8);
        #pragma unroll
        for (int ni = 0; ni < 4; ++ni)
            bfg[ni] = *(const bf16x8*)(Bs + (wn + ni * 16 + ml) * LSTR + kg * 8);
        #pragma unroll
        for (int mi = 0; mi < 4; ++mi)
            #pragma unroll
            for (int ni = 0; ni < 4; ++ni)
                acc[mi][ni] = __builtin_amdgcn_mfma_f32_16x16x32_bf16(af[mi], bfg[ni], acc[mi][ni], 0, 0, 0);
        __syncthreads();
    }

    float bias[4];
    #pragma unroll
    for (int ni = 0; ni < 4; ++ni)
        bias[ni] = b2[(size_t)e * DM + nb + wn + ni * 16 + ml];

    #pragma unroll
    for (int mi = 0; mi < 4; ++mi) {
        #pragma unroll
        for (int r = 0; r < 4; ++r) {
            int row = wm + mi * 16 + kg * 4 + r;
            int s = slot_s[row];
            if (s < 0) continue;
            float g = gate_s[row];
            float* orow = out + (size_t)(s >> 1) * DM + nb;
            #pragma unroll
            for (int ni = 0; ni < 4; ++ni) {
                float v = acc[mi][ni][r] + bias[ni];
                atomicAdd(orow + wn + ni * 16 + ml, g * v);
            }
        }
    }
}

extern "C" void kernel_launch(void* const* d_in, const int* in_sizes, int n_in,
                              void* d_out, int out_size, void* d_ws, size_t ws_size,
                              hipStream_t stream) {
    const float* x     = (const float*)d_in[0];
    const float* noise = (const float*)d_in[1];
    const float* Wg    = (const float*)d_in[2];
    const float* bg    = (const float*)d_in[3];
    const float* Wn    = (const float*)d_in[4];
    const float* bn    = (const float*)d_in[5];
    const float* W1    = (const float*)d_in[6];
    const float* b1    = (const float*)d_in[7];
    const float* W2    = (const float*)d_in[8];
    const float* b2    = (const float*)d_in[9];
    float* out = (float*)d_out;

    char* ws = (char*)d_ws;
    int*   counts = (int*)ws;                                   // 8 ints (1 KiB reserved)
    int*   slots  = (int*)(ws + 1024);                          // [E][T] int32
    float* gates  = (float*)(ws + 1024 + NE * T_TOK * 4);       // [E][T] f32
    unsigned short* h = (unsigned short*)(ws + 1024 + 2 * NE * T_TOK * 4); // [2T][F] bf16, 67 MB

    hipMemsetAsync(counts, 0, 1024, stream);
    hipMemsetAsync(out, 0, (size_t)out_size * sizeof(float), stream);

    k_router<<<T_TOK / 4, 256, 0, stream>>>(x, noise, Wg, bg, Wn, bn, counts, slots, gates);

    dim3 g1(DF / BN, T_TOK / BM, NE);   // (32, 32, 8); idle tiles early-exit
    k_fc1<<<g1, 256, 0, stream>>>(x, W1, b1, counts, slots, h);

    dim3 g2(DM / BN, T_TOK / BM, NE);   // (8, 32, 8)
    k_fc2<<<g2, 256, 0, stream>>>(h, W2, b2, counts, slots, gates, out);
}

// Round 2
// 823.632 us; speedup vs baseline: 1.0539x; 1.0539x over previous
//
#include <hip/hip_runtime.h>
#include <math.h>

#define T_TOK 4096
#define DM 1024
#define DF 4096
#define NE 8

#define BM 128
#define BN 128
#define BK 64   // bf16 elems; 128 B per LDS row

typedef __attribute__((ext_vector_type(8))) short bf16x8;
typedef __attribute__((ext_vector_type(4))) float f32x4;
typedef unsigned long long u64;

__device__ __forceinline__ unsigned short f2bf(float f) {
    union { float f; unsigned int u; } v; v.f = f;
    unsigned int r = v.u + 0x7FFFu + ((v.u >> 16) & 1u);
    return (unsigned short)(r >> 16);
}

__device__ __forceinline__ void glds16(const void* g, void* l) {
    __builtin_amdgcn_global_load_lds(
        (const __attribute__((address_space(1))) unsigned int*)g,
        (__attribute__((address_space(3))) unsigned int*)l, 16, 0, 0);
}

// ---------------- router: 1 wave per token ----------------
__global__ __launch_bounds__(256) void k_router(
    const float* __restrict__ x, const float* __restrict__ noise,
    const float* __restrict__ Wg, const float* __restrict__ bg,
    const float* __restrict__ Wn, const float* __restrict__ bn,
    int* __restrict__ counts, int* __restrict__ slots, float* __restrict__ gates)
{
    const int lane = threadIdx.x & 63;
    const int wave = threadIdx.x >> 6;
    const int t = blockIdx.x * 4 + wave;
    const float* xr = x + (size_t)t * DM + lane * 16;

    float accg[8], accn[8];
    #pragma unroll
    for (int i = 0; i < 8; ++i) { accg[i] = 0.f; accn[i] = 0.f; }

    #pragma unroll
    for (int dd = 0; dd < 16; ++dd) {
        float xv = xr[dd];
        int d = lane * 16 + dd;
        float4 g0 = *(const float4*)(Wg + d * 8);
        float4 g1 = *(const float4*)(Wg + d * 8 + 4);
        float4 n0 = *(const float4*)(Wn + d * 8);
        float4 n1 = *(const float4*)(Wn + d * 8 + 4);
        accg[0] += xv * g0.x; accg[1] += xv * g0.y; accg[2] += xv * g0.z; accg[3] += xv * g0.w;
        accg[4] += xv * g1.x; accg[5] += xv * g1.y; accg[6] += xv * g1.z; accg[7] += xv * g1.w;
        accn[0] += xv * n0.x; accn[1] += xv * n0.y; accn[2] += xv * n0.z; accn[3] += xv * n0.w;
        accn[4] += xv * n1.x; accn[5] += xv * n1.y; accn[6] += xv * n1.z; accn[7] += xv * n1.w;
    }
    #pragma unroll
    for (int s = 1; s < 64; s <<= 1) {
        #pragma unroll
        for (int e = 0; e < 8; ++e) {
            accg[e] += __shfl_xor(accg[e], s, 64);
            accn[e] += __shfl_xor(accn[e], s, 64);
        }
    }
    if (lane == 0) {
        float nv[8];
        #pragma unroll
        for (int e = 0; e < 8; ++e) {
            float lg = accg[e] + bg[e];
            float nl = accn[e] + bn[e];
            float sp = (nl > 20.f) ? nl : log1pf(expf(nl));
            nv[e] = lg + noise[(size_t)t * NE + e] * sp;
        }
        int i0 = 0;
        #pragma unroll
        for (int e = 1; e < 8; ++e) if (nv[e] > nv[i0]) i0 = e;
        int i1 = -1;
        #pragma unroll
        for (int e = 0; e < 8; ++e) {
            if (e == i0) continue;
            if (i1 < 0 || nv[e] > nv[i1]) i1 = e;
        }
        float ex = expf(nv[i1] - nv[i0]);     // <= 1
        float g0 = 1.f / (1.f + ex);
        float g1 = ex / (1.f + ex);
        int p0 = atomicAdd(counts + i0, 1);
        slots[i0 * T_TOK + p0] = t * 2;     gates[i0 * T_TOK + p0] = g0;
        int p1 = atomicAdd(counts + i1, 1);
        slots[i1 * T_TOK + p1] = t * 2 + 1; gates[i1 * T_TOK + p1] = g1;
    }
}

// ---------------- x f32 -> bf16 ----------------
__global__ __launch_bounds__(256) void k_xcast(const float* __restrict__ x,
                                               unsigned short* __restrict__ xb)
{
    int i = blockIdx.x * 256 + threadIdx.x;
    float4 v = ((const float4*)x)[i];
    u64 p = (u64)f2bf(v.x) | ((u64)f2bf(v.y) << 16) | ((u64)f2bf(v.z) << 32) | ((u64)f2bf(v.w) << 48);
    ((u64*)xb)[i] = p;
}

// ---------------- transpose+convert: in [E][R][C] f32 -> out [E][C][R] bf16 ----------------
__global__ __launch_bounds__(256) void k_tr(const float* __restrict__ in,
                                            unsigned short* __restrict__ out,
                                            int R, int C)
{
    __shared__ unsigned short t[64 * 68];   // +4 pad breaks bank alignment
    const int e = blockIdx.z;
    const int C0 = blockIdx.x * 64, R0 = blockIdx.y * 64;
    const float* ip = in + ((size_t)e * R + R0) * C + C0;
    unsigned short* op = out + ((size_t)e * C + C0) * R + R0;
    const int tid = threadIdx.x;

    #pragma unroll
    for (int p = 0; p < 4; ++p) {
        int r = p * 16 + (tid >> 4), c4 = (tid & 15) * 4;
        float4 v = *(const float4*)(ip + (size_t)r * C + c4);
        t[(c4 + 0) * 68 + r] = f2bf(v.x);
        t[(c4 + 1) * 68 + r] = f2bf(v.y);
        t[(c4 + 2) * 68 + r] = f2bf(v.z);
        t[(c4 + 3) * 68 + r] = f2bf(v.w);
    }
    __syncthreads();
    #pragma unroll
    for (int p = 0; p < 4; ++p) {
        int c = p * 16 + (tid >> 4), r4 = (tid & 15) * 4;
        u64 v = *(const u64*)(t + c * 68 + r4);
        *(u64*)(op + (size_t)c * R + r4) = v;
    }
}

// ---------------- fc1: h[slot] = relu(x_bf[tok] @ W1t^T + b1) ----------------
// W1t layout: [E][F][D] bf16 (n-major, k contiguous)
__global__ __launch_bounds__(256) void k_fc1(
    const unsigned short* __restrict__ xb, const unsigned short* __restrict__ W1t,
    const float* __restrict__ b1, const int* __restrict__ counts,
    const int* __restrict__ slots, unsigned short* __restrict__ h)
{
    const int e = blockIdx.z;
    const int cnt = counts[e];
    const int mt = blockIdx.y;
    if (mt * BM >= cnt) return;
    const int nb = blockIdx.x * BN;

    __shared__ unsigned short As[BM * BK];
    __shared__ unsigned short Bs[BN * BK];
    __shared__ int slot_s[BM];

    const int tid = threadIdx.x;
    if (tid < BM) {
        int gi = mt * BM + tid;
        slot_s[tid] = (gi < cnt) ? slots[e * T_TOK + gi] : -1;
    }
    __syncthreads();

    const int lane = tid & 63, wv = tid >> 6;
    const int wm = (wv & 1) * 64, wn = (wv >> 1) * 64;
    const int ml = lane & 15, kg = lane >> 4;

    // staging geometry: per call c, this thread feeds LDS row c*32+(tid>>3),
    // physical 16B-chunk tid&7; swizzle: fetch global chunk (tid&7)^(row&7)
    const int srow = tid >> 3;
    const int cg = (tid & 7) ^ (srow & 7);

    const unsigned short* ag[4];
    const unsigned short* bg[4];
    const unsigned short* wbase = W1t + (size_t)e * DF * DM;
    #pragma unroll
    for (int c = 0; c < 4; ++c) {
        int row = c * 32 + srow;
        int s = slot_s[row];
        int tok = (s >= 0) ? (s >> 1) : 0;
        ag[c] = xb + (size_t)tok * DM + cg * 8;
        bg[c] = wbase + (size_t)(nb + row) * DM + cg * 8;
    }
    unsigned short* al = As + wv * 512;   // wave-uniform LDS base (+ c*2048)
    unsigned short* bl = Bs + wv * 512;

    f32x4 acc[4][4];
    #pragma unroll
    for (int ni = 0; ni < 4; ++ni)
        #pragma unroll
        for (int mi = 0; mi < 4; ++mi) acc[ni][mi] = (f32x4){0.f, 0.f, 0.f, 0.f};

    for (int k0 = 0; k0 < DM; k0 += BK) {
        #pragma unroll
        for (int c = 0; c < 4; ++c) glds16(ag[c] + k0, al + c * 2048);
        #pragma unroll
        for (int c = 0; c < 4; ++c) glds16(bg[c] + k0, bl + c * 2048);
        __syncthreads();
        #pragma unroll
        for (int ks = 0; ks < 2; ++ks) {
            const int ch = (((ks * 4 + kg) ^ (ml & 7)) << 3);
            bf16x8 af[4], bf[4];
            #pragma unroll
            for (int mi = 0; mi < 4; ++mi)
                af[mi] = *(const bf16x8*)(As + (wm + mi * 16 + ml) * BK + ch);
            #pragma unroll
            for (int ni = 0; ni < 4; ++ni)
                bf[ni] = *(const bf16x8*)(Bs + (wn + ni * 16 + ml) * BK + ch);
            #pragma unroll
            for (int ni = 0; ni < 4; ++ni)
                #pragma unroll
                for (int mi = 0; mi < 4; ++mi)
                    acc[ni][mi] = __builtin_amdgcn_mfma_f32_16x16x32_bf16(bf[ni], af[mi], acc[ni][mi], 0, 0, 0);
        }
        __syncthreads();
    }

    // D layout (swapped operands): col=ml -> token row; row=kg*4+j -> n (output feature)
    #pragma unroll
    for (int mi = 0; mi < 4; ++mi) {
        int s = slot_s[wm + mi * 16 + ml];
        if (s < 0) continue;
        #pragma unroll
        for (int ni = 0; ni < 4; ++ni) {
            int n0 = wn + ni * 16 + kg * 4;
            float4 bb = *(const float4*)(b1 + (size_t)e * DF + nb + n0);
            float v0 = fmaxf(acc[ni][mi][0] + bb.x, 0.f);
            float v1 = fmaxf(acc[ni][mi][1] + bb.y, 0.f);
            float v2 = fmaxf(acc[ni][mi][2] + bb.z, 0.f);
            float v3 = fmaxf(acc[ni][mi][3] + bb.w, 0.f);
            u64 p = (u64)f2bf(v0) | ((u64)f2bf(v1) << 16) | ((u64)f2bf(v2) << 32) | ((u64)f2bf(v3) << 48);
            *(u64*)(h + (size_t)s * DF + nb + n0) = p;
        }
    }
}

// ---------------- fc2: out[tok] += gate * (h[slot] @ W2t^T + b2), split-K=2 ----------------
// W2t layout: [E][D][F] bf16
__global__ __launch_bounds__(256) void k_fc2(
    const unsigned short* __restrict__ h, const unsigned short* __restrict__ W2t,
    const float* __restrict__ b2, const int* __restrict__ counts,
    const int* __restrict__ slots, const float* __restrict__ gates,
    float* __restrict__ out)
{
    const int e = blockIdx.z >> 1;
    const int kz = blockIdx.z & 1;
    const int cnt = counts[e];
    const int mt = blockIdx.y;
    if (mt * BM >= cnt) return;
    const int nb = blockIdx.x * BN;

    __shared__ unsigned short As[BM * BK];
    __shared__ unsigned short Bs[BN * BK];
    __shared__ int slot_s[BM];
    __shared__ float gate_s[BM];

    const int tid = threadIdx.x;
    if (tid < BM) {
        int gi = mt * BM + tid;
        if (gi < cnt) {
            slot_s[tid] = slots[e * T_TOK + gi];
            gate_s[tid] = gates[e * T_TOK + gi];
        } else { slot_s[tid] = -1; gate_s[tid] = 0.f; }
    }
    __syncthreads();

    const int lane = tid & 63, wv = tid >> 6;
    const int wm = (wv & 1) * 64, wn = (wv >> 1) * 64;
    const int ml = lane & 15, kg = lane >> 4;

    const int srow = tid >> 3;
    const int cg = (tid & 7) ^ (srow & 7);

    const unsigned short* ag[4];
    const unsigned short* bg[4];
    const unsigned short* wbase = W2t + (size_t)e * DM * DF;
    #pragma unroll
    for (int c = 0; c < 4; ++c) {
        int row = c * 32 + srow;
        int s = slot_s[row];
        int sl = (s >= 0) ? s : 0;
        ag[c] = h + (size_t)sl * DF + cg * 8;
        bg[c] = wbase + (size_t)(nb + row) * DF + cg * 8;
    }
    unsigned short* al = As + wv * 512;
    unsigned short* bl = Bs + wv * 512;

    f32x4 acc[4][4];
    #pragma unroll
    for (int ni = 0; ni < 4; ++ni)
        #pragma unroll
        for (int mi = 0; mi < 4; ++mi) acc[ni][mi] = (f32x4){0.f, 0.f, 0.f, 0.f};

    const int kbeg = kz * (DF / 2), kend = kbeg + DF / 2;
    for (int k0 = kbeg; k0 < kend; k0 += BK) {
        #pragma unroll
        for (int c = 0; c < 4; ++c) glds16(ag[c] + k0, al + c * 2048);
        #pragma unroll
        for (int c = 0; c < 4; ++c) glds16(bg[c] + k0, bl + c * 2048);
        __syncthreads();
        #pragma unroll
        for (int ks = 0; ks < 2; ++ks) {
            const int ch = (((ks * 4 + kg) ^ (ml & 7)) << 3);
            bf16x8 af[4], bf[4];
            #pragma unroll
            for (int mi = 0; mi < 4; ++mi)
                af[mi] = *(const bf16x8*)(As + (wm + mi * 16 + ml) * BK + ch);
            #pragma unroll
            for (int ni = 0; ni < 4; ++ni)
                bf[ni] = *(const bf16x8*)(Bs + (wn + ni * 16 + ml) * BK + ch);
            #pragma unroll
            for (int ni = 0; ni < 4; ++ni)
                #pragma unroll
                for (int mi = 0; mi < 4; ++mi)
                    acc[ni][mi] = __builtin_amdgcn_mfma_f32_16x16x32_bf16(bf[ni], af[mi], acc[ni][mi], 0, 0, 0);
        }
        __syncthreads();
    }

    #pragma unroll
    for (int mi = 0; mi < 4; ++mi) {
        int s = slot_s[wm + mi * 16 + ml];
        if (s < 0) continue;
        float g = gate_s[wm + mi * 16 + ml];
        float* orow = out + (size_t)(s >> 1) * DM + nb;
        #pragma unroll
        for (int ni = 0; ni < 4; ++ni) {
            int n0 = wn + ni * 16 + kg * 4;
            float4 bb;
            if (kz == 0) bb = *(const float4*)(b2 + (size_t)e * DM + nb + n0);
            else         bb = make_float4(0.f, 0.f, 0.f, 0.f);
            atomicAdd(orow + n0 + 0, g * (acc[ni][mi][0] + bb.x));
            atomicAdd(orow + n0 + 1, g * (acc[ni][mi][1] + bb.y));
            atomicAdd(orow + n0 + 2, g * (acc[ni][mi][2] + bb.z));
            atomicAdd(orow + n0 + 3, g * (acc[ni][mi][3] + bb.w));
        }
    }
}

extern "C" void kernel_launch(void* const* d_in, const int* in_sizes, int n_in,
                              void* d_out, int out_size, void* d_ws, size_t ws_size,
                              hipStream_t stream) {
    const float* x     = (const float*)d_in[0];
    const float* noise = (const float*)d_in[1];
    const float* Wg    = (const float*)d_in[2];
    const float* bg    = (const float*)d_in[3];
    const float* Wn    = (const float*)d_in[4];
    const float* bn    = (const float*)d_in[5];
    const float* W1    = (const float*)d_in[6];
    const float* b1    = (const float*)d_in[7];
    const float* W2    = (const float*)d_in[8];
    const float* b2    = (const float*)d_in[9];
    float* out = (float*)d_out;

    char* ws = (char*)d_ws;
    int*   counts = (int*)ws;                                    // 4 KiB reserved
    int*   slots  = (int*)(ws + 4096);                           // [E][T] int32
    float* gates  = (float*)(ws + 4096 + NE * T_TOK * 4);        // [E][T] f32
    unsigned short* xb = (unsigned short*)(ws + 4096 + 2 * NE * T_TOK * 4); // [T][D] bf16, 8 MB
    unsigned short* hh = xb + (size_t)T_TOK * DM;                // [2T][F] bf16, 67 MB
    unsigned short* Wt = hh + (size_t)2 * T_TOK * DF;            // [E][*][*] bf16, 67 MB (reused W1t then W2t)

    hipMemsetAsync(counts, 0, 4096, stream);
    hipMemsetAsync(out, 0, (size_t)out_size * sizeof(float), stream);

    k_router<<<T_TOK / 4, 256, 0, stream>>>(x, noise, Wg, bg, Wn, bn, counts, slots, gates);
    k_xcast<<<T_TOK * DM / 1024, 256, 0, stream>>>(x, xb);

    // W1 [E][D][F] -> Wt [E][F][D]
    k_tr<<<dim3(DF / 64, DM / 64, NE), 256, 0, stream>>>(W1, Wt, DM, DF);
    k_fc1<<<dim3(DF / BN, T_TOK / BM, NE), 256, 0, stream>>>(xb, Wt, b1, counts, slots, hh);

    // W2 [E][F][D] -> Wt [E][D][F]   (reuses the same buffer after fc1 is done)
    k_tr<<<dim3(DM / 64, DF / 64, NE), 256, 0, stream>>>(W2, Wt, DF, DM);
    k_fc2<<<dim3(DM / BN, T_TOK / BM, NE * 2), 256, 0, stream>>>(hh, Wt, b2, counts, slots, gates, out);
}

// Round 3
// 670.078 us; speedup vs baseline: 1.2954x; 1.2292x over previous
//
#include <hip/hip_runtime.h>
#include <math.h>

#define T_TOK 4096
#define DM 1024
#define DF 4096
#define NE 8

#define BM 128
#define BN 128
#define BK 32   // bf16 elems per K-step; 64 B per LDS row

typedef __attribute__((ext_vector_type(8))) short bf16x8;
typedef __attribute__((ext_vector_type(4))) float f32x4;
typedef unsigned long long u64;

__device__ __forceinline__ unsigned short f2bf(float f) {
    union { float f; unsigned int u; } v; v.f = f;
    unsigned int r = v.u + 0x7FFFu + ((v.u >> 16) & 1u);
    return (unsigned short)(r >> 16);
}
__device__ __forceinline__ float bf2f(unsigned short u) {
    union { float f; unsigned int u; } v; v.u = ((unsigned int)u) << 16;
    return v.f;
}

__device__ __forceinline__ void glds16(const void* g, void* l) {
    __builtin_amdgcn_global_load_lds(
        (const __attribute__((address_space(1))) unsigned int*)g,
        (__attribute__((address_space(3))) unsigned int*)l, 16, 0, 0);
}

// ---------------- router: 1 wave per token ----------------
__global__ __launch_bounds__(256) void k_router(
    const float* __restrict__ x, const float* __restrict__ noise,
    const float* __restrict__ Wg, const float* __restrict__ bg,
    const float* __restrict__ Wn, const float* __restrict__ bn,
    int* __restrict__ counts, int* __restrict__ slots, float* __restrict__ gates)
{
    const int lane = threadIdx.x & 63;
    const int wave = threadIdx.x >> 6;
    const int t = blockIdx.x * 4 + wave;
    const float* xr = x + (size_t)t * DM + lane * 16;

    float accg[8], accn[8];
    #pragma unroll
    for (int i = 0; i < 8; ++i) { accg[i] = 0.f; accn[i] = 0.f; }

    #pragma unroll
    for (int dd = 0; dd < 16; ++dd) {
        float xv = xr[dd];
        int d = lane * 16 + dd;
        float4 g0 = *(const float4*)(Wg + d * 8);
        float4 g1 = *(const float4*)(Wg + d * 8 + 4);
        float4 n0 = *(const float4*)(Wn + d * 8);
        float4 n1 = *(const float4*)(Wn + d * 8 + 4);
        accg[0] += xv * g0.x; accg[1] += xv * g0.y; accg[2] += xv * g0.z; accg[3] += xv * g0.w;
        accg[4] += xv * g1.x; accg[5] += xv * g1.y; accg[6] += xv * g1.z; accg[7] += xv * g1.w;
        accn[0] += xv * n0.x; accn[1] += xv * n0.y; accn[2] += xv * n0.z; accn[3] += xv * n0.w;
        accn[4] += xv * n1.x; accn[5] += xv * n1.y; accn[6] += xv * n1.z; accn[7] += xv * n1.w;
    }
    #pragma unroll
    for (int s = 1; s < 64; s <<= 1) {
        #pragma unroll
        for (int e = 0; e < 8; ++e) {
            accg[e] += __shfl_xor(accg[e], s, 64);
            accn[e] += __shfl_xor(accn[e], s, 64);
        }
    }
    if (lane == 0) {
        float nv[8];
        #pragma unroll
        for (int e = 0; e < 8; ++e) {
            float lg = accg[e] + bg[e];
            float nl = accn[e] + bn[e];
            float sp = (nl > 20.f) ? nl : log1pf(expf(nl));
            nv[e] = lg + noise[(size_t)t * NE + e] * sp;
        }
        int i0 = 0;
        #pragma unroll
        for (int e = 1; e < 8; ++e) if (nv[e] > nv[i0]) i0 = e;
        int i1 = -1;
        #pragma unroll
        for (int e = 0; e < 8; ++e) {
            if (e == i0) continue;
            if (i1 < 0 || nv[e] > nv[i1]) i1 = e;
        }
        float ex = expf(nv[i1] - nv[i0]);     // <= 1
        float g0 = 1.f / (1.f + ex);
        float g1 = ex / (1.f + ex);
        int p0 = atomicAdd(counts + i0, 1);
        slots[i0 * T_TOK + p0] = t * 2;     gates[i0 * T_TOK + p0] = g0;
        int p1 = atomicAdd(counts + i1, 1);
        slots[i1 * T_TOK + p1] = t * 2 + 1; gates[i1 * T_TOK + p1] = g1;
    }
}

// ---------------- x f32 -> bf16 ----------------
__global__ __launch_bounds__(256) void k_xcast(const float* __restrict__ x,
                                               unsigned short* __restrict__ xb)
{
    int i = blockIdx.x * 256 + threadIdx.x;
    float4 v = ((const float4*)x)[i];
    u64 p = (u64)f2bf(v.x) | ((u64)f2bf(v.y) << 16) | ((u64)f2bf(v.z) << 32) | ((u64)f2bf(v.w) << 48);
    ((u64*)xb)[i] = p;
}

// ---------------- transpose+convert: in [E][R][C] f32 -> out [E][C][R] bf16 ----------------
__global__ __launch_bounds__(256) void k_tr(const float* __restrict__ in,
                                            unsigned short* __restrict__ out,
                                            int R, int C)
{
    __shared__ unsigned short t[64 * 68];
    const int e = blockIdx.z;
    const int C0 = blockIdx.x * 64, R0 = blockIdx.y * 64;
    const float* ip = in + ((size_t)e * R + R0) * C + C0;
    unsigned short* op = out + ((size_t)e * C + C0) * R + R0;
    const int tid = threadIdx.x;

    #pragma unroll
    for (int p = 0; p < 4; ++p) {
        int r = p * 16 + (tid >> 4), c4 = (tid & 15) * 4;
        float4 v = *(const float4*)(ip + (size_t)r * C + c4);
        t[(c4 + 0) * 68 + r] = f2bf(v.x);
        t[(c4 + 1) * 68 + r] = f2bf(v.y);
        t[(c4 + 2) * 68 + r] = f2bf(v.z);
        t[(c4 + 3) * 68 + r] = f2bf(v.w);
    }
    __syncthreads();
    #pragma unroll
    for (int p = 0; p < 4; ++p) {
        int c = p * 16 + (tid >> 4), r4 = (tid & 15) * 4;
        u64 v = *(const u64*)(t + c * 68 + r4);
        *(u64*)(op + (size_t)c * R + r4) = v;
    }
}

// ---------------- fc1: h[slot] = relu(x_bf[tok] @ W1t^T + b1) ----------------
// W1t layout: [E][F][D] bf16 (n-major, k contiguous). grid = (NE, DF/BN, T/BM)
__global__ __launch_bounds__(256, 4) void k_fc1(
    const unsigned short* __restrict__ xb, const unsigned short* __restrict__ W1t,
    const float* __restrict__ b1, const int* __restrict__ counts,
    const int* __restrict__ slots, unsigned short* __restrict__ h)
{
    const int e = blockIdx.x;          // expert in x => expert-XCD affinity
    const int cnt = counts[e];
    const int mt = blockIdx.z;
    if (mt * BM >= cnt) return;
    const int nb = blockIdx.y * BN;

    __shared__ unsigned short As[2][BM * BK];
    __shared__ unsigned short Bs[2][BN * BK];
    __shared__ int slot_s[BM];

    const int tid = threadIdx.x;
    if (tid < BM) {
        int gi = mt * BM + tid;
        slot_s[tid] = (gi < cnt) ? slots[e * T_TOK + gi] : -1;
    }
    __syncthreads();

    // staging: thread -> (row = c*64 + tid>>2, phys chunk = tid&3)
    // global chunk = (tid&3) ^ ((tid>>3)&3)  (reader: kg ^ ((ml>>1)&3) -> 2-way, free)
    const int srow = tid >> 2;
    const int cg = (tid & 3) ^ ((tid >> 3) & 3);

    const unsigned short* ag[2];
    const unsigned short* bgp[2];
    const unsigned short* wbase = W1t + (size_t)e * DF * DM;
    #pragma unroll
    for (int c = 0; c < 2; ++c) {
        int row = c * 64 + srow;
        int s = slot_s[row];
        int tok = (s >= 0) ? (s >> 1) : 0;
        ag[c]  = xb + (size_t)tok * DM + cg * 8;
        bgp[c] = wbase + (size_t)(nb + row) * DM + cg * 8;
    }

    const int lane = tid & 63, wv = tid >> 6;
    const int wm = (wv & 1) * 64, wn = (wv >> 1) * 64;
    const int ml = lane & 15, kg = lane >> 4;
    const int rch = (kg ^ ((ml >> 1) & 3)) * 8;
    const int lo = wv * 512;   // shorts: per-wave LDS chunk within each half

    f32x4 acc[4][4];
    #pragma unroll
    for (int ni = 0; ni < 4; ++ni)
        #pragma unroll
        for (int mi = 0; mi < 4; ++mi) acc[ni][mi] = (f32x4){0.f, 0.f, 0.f, 0.f};

    #pragma unroll
    for (int c = 0; c < 2; ++c) glds16(ag[c],  &As[0][c * 2048 + lo]);
    #pragma unroll
    for (int c = 0; c < 2; ++c) glds16(bgp[c], &Bs[0][c * 2048 + lo]);

    int buf = 0;
    for (int k0 = 0; k0 < DM; k0 += BK) {
        __syncthreads();   // drains vmcnt: buf's loads (in flight during prior compute) ready
        if (k0 + BK < DM) {
            #pragma unroll
            for (int c = 0; c < 2; ++c) glds16(ag[c] + k0 + BK,  &As[buf ^ 1][c * 2048 + lo]);
            #pragma unroll
            for (int c = 0; c < 2; ++c) glds16(bgp[c] + k0 + BK, &Bs[buf ^ 1][c * 2048 + lo]);
        }
        bf16x8 af[4], bfr[4];
        #pragma unroll
        for (int mi = 0; mi < 4; ++mi)
            af[mi] = *(const bf16x8*)(&As[buf][(wm + mi * 16 + ml) * BK + rch]);
        #pragma unroll
        for (int ni = 0; ni < 4; ++ni)
            bfr[ni] = *(const bf16x8*)(&Bs[buf][(wn + ni * 16 + ml) * BK + rch]);
        #pragma unroll
        for (int ni = 0; ni < 4; ++ni)
            #pragma unroll
            for (int mi = 0; mi < 4; ++mi)
                acc[ni][mi] = __builtin_amdgcn_mfma_f32_16x16x32_bf16(bfr[ni], af[mi], acc[ni][mi], 0, 0, 0);
        buf ^= 1;
    }

    // D layout (swapped operands): col=ml -> token row; row=kg*4+j -> n
    #pragma unroll
    for (int mi = 0; mi < 4; ++mi) {
        int s = slot_s[wm + mi * 16 + ml];
        if (s < 0) continue;
        #pragma unroll
        for (int ni = 0; ni < 4; ++ni) {
            int n0 = wn + ni * 16 + kg * 4;
            float4 bb = *(const float4*)(b1 + (size_t)e * DF + nb + n0);
            float v0 = fmaxf(acc[ni][mi][0] + bb.x, 0.f);
            float v1 = fmaxf(acc[ni][mi][1] + bb.y, 0.f);
            float v2 = fmaxf(acc[ni][mi][2] + bb.z, 0.f);
            float v3 = fmaxf(acc[ni][mi][3] + bb.w, 0.f);
            u64 p = (u64)f2bf(v0) | ((u64)f2bf(v1) << 16) | ((u64)f2bf(v2) << 32) | ((u64)f2bf(v3) << 48);
            *(u64*)(h + (size_t)s * DF + nb + n0) = p;
        }
    }
}

// ---------------- fc2: eo[kz][slot] = gate*(h[slot] @ W2t^T + b2*(kz==0)) ----------------
// W2t layout: [E][D][F] bf16. grid = (NE, DM/BN, (T/BM)*2)
__global__ __launch_bounds__(256, 4) void k_fc2(
    const unsigned short* __restrict__ h, const unsigned short* __restrict__ W2t,
    const float* __restrict__ b2, const int* __restrict__ counts,
    const int* __restrict__ slots, const float* __restrict__ gates,
    unsigned short* __restrict__ eo)
{
    const int e = blockIdx.x;
    const int cnt = counts[e];
    const int mt = blockIdx.z >> 1;
    const int kz = blockIdx.z & 1;
    if (mt * BM >= cnt) return;
    const int nb = blockIdx.y * BN;

    __shared__ unsigned short As[2][BM * BK];
    __shared__ unsigned short Bs[2][BN * BK];
    __shared__ int slot_s[BM];
    __shared__ float gate_s[BM];

    const int tid = threadIdx.x;
    if (tid < BM) {
        int gi = mt * BM + tid;
        if (gi < cnt) {
            slot_s[tid] = slots[e * T_TOK + gi];
            gate_s[tid] = gates[e * T_TOK + gi];
        } else { slot_s[tid] = -1; gate_s[tid] = 0.f; }
    }
    __syncthreads();

    const int srow = tid >> 2;
    const int cg = (tid & 3) ^ ((tid >> 3) & 3);
    const int kbeg = kz * (DF / 2);

    const unsigned short* ag[2];
    const unsigned short* bgp[2];
    const unsigned short* wbase = W2t + (size_t)e * DM * DF;
    #pragma unroll
    for (int c = 0; c < 2; ++c) {
        int row = c * 64 + srow;
        int s = slot_s[row];
        int sl = (s >= 0) ? s : 0;
        ag[c]  = h + (size_t)sl * DF + kbeg + cg * 8;
        bgp[c] = wbase + (size_t)(nb + row) * DF + kbeg + cg * 8;
    }

    const int lane = tid & 63, wv = tid >> 6;
    const int wm = (wv & 1) * 64, wn = (wv >> 1) * 64;
    const int ml = lane & 15, kg = lane >> 4;
    const int rch = (kg ^ ((ml >> 1) & 3)) * 8;
    const int lo = wv * 512;

    f32x4 acc[4][4];
    #pragma unroll
    for (int ni = 0; ni < 4; ++ni)
        #pragma unroll
        for (int mi = 0; mi < 4; ++mi) acc[ni][mi] = (f32x4){0.f, 0.f, 0.f, 0.f};

    #pragma unroll
    for (int c = 0; c < 2; ++c) glds16(ag[c],  &As[0][c * 2048 + lo]);
    #pragma unroll
    for (int c = 0; c < 2; ++c) glds16(bgp[c], &Bs[0][c * 2048 + lo]);

    int buf = 0;
    for (int k0 = 0; k0 < DF / 2; k0 += BK) {
        __syncthreads();
        if (k0 + BK < DF / 2) {
            #pragma unroll
            for (int c = 0; c < 2; ++c) glds16(ag[c] + k0 + BK,  &As[buf ^ 1][c * 2048 + lo]);
            #pragma unroll
            for (int c = 0; c < 2; ++c) glds16(bgp[c] + k0 + BK, &Bs[buf ^ 1][c * 2048 + lo]);
        }
        bf16x8 af[4], bfr[4];
        #pragma unroll
        for (int mi = 0; mi < 4; ++mi)
            af[mi] = *(const bf16x8*)(&As[buf][(wm + mi * 16 + ml) * BK + rch]);
        #pragma unroll
        for (int ni = 0; ni < 4; ++ni)
            bfr[ni] = *(const bf16x8*)(&Bs[buf][(wn + ni * 16 + ml) * BK + rch]);
        #pragma unroll
        for (int ni = 0; ni < 4; ++ni)
            #pragma unroll
            for (int mi = 0; mi < 4; ++mi)
                acc[ni][mi] = __builtin_amdgcn_mfma_f32_16x16x32_bf16(bfr[ni], af[mi], acc[ni][mi], 0, 0, 0);
        buf ^= 1;
    }

    unsigned short* eob = eo + (size_t)kz * 2 * T_TOK * DM;
    #pragma unroll
    for (int mi = 0; mi < 4; ++mi) {
        int s = slot_s[wm + mi * 16 + ml];
        if (s < 0) continue;
        float g = gate_s[wm + mi * 16 + ml];
        #pragma unroll
        for (int ni = 0; ni < 4; ++ni) {
            int n0 = wn + ni * 16 + kg * 4;
            float4 bb;
            if (kz == 0) bb = *(const float4*)(b2 + (size_t)e * DM + nb + n0);
            else         bb = make_float4(0.f, 0.f, 0.f, 0.f);
            float v0 = g * (acc[ni][mi][0] + bb.x);
            float v1 = g * (acc[ni][mi][1] + bb.y);
            float v2 = g * (acc[ni][mi][2] + bb.z);
            float v3 = g * (acc[ni][mi][3] + bb.w);
            u64 p = (u64)f2bf(v0) | ((u64)f2bf(v1) << 16) | ((u64)f2bf(v2) << 32) | ((u64)f2bf(v3) << 48);
            *(u64*)(eob + (size_t)s * DM + nb + n0) = p;
        }
    }
}

// ---------------- combine: out[t] = sum over {kz} x {2t,2t+1} of eo ----------------
__global__ __launch_bounds__(256) void k_comb(const unsigned short* __restrict__ eo,
                                              float* __restrict__ out)
{
    int i = blockIdx.x * 256 + threadIdx.x;   // float4 index over T*DM/4
    int t = i >> 8;                           // DM/4 = 256
    int d4 = (i & 255) * 4;
    const unsigned short* p0 = eo + (size_t)(2 * t) * DM + d4;
    const unsigned short* p1 = p0 + DM;
    const unsigned short* q0 = p0 + (size_t)2 * T_TOK * DM;
    const unsigned short* q1 = q0 + DM;
    ushort4 a0 = *(const ushort4*)p0;
    ushort4 a1 = *(const ushort4*)p1;
    ushort4 b0 = *(const ushort4*)q0;
    ushort4 b1 = *(const ushort4*)q1;
    float4 r;
    r.x = bf2f(a0.x) + bf2f(a1.x) + bf2f(b0.x) + bf2f(b1.x);
    r.y = bf2f(a0.y) + bf2f(a1.y) + bf2f(b0.y) + bf2f(b1.y);
    r.z = bf2f(a0.z) + bf2f(a1.z) + bf2f(b0.z) + bf2f(b1.z);
    r.w = bf2f(a0.w) + bf2f(a1.w) + bf2f(b0.w) + bf2f(b1.w);
    ((float4*)out)[i] = r;
}

extern "C" void kernel_launch(void* const* d_in, const int* in_sizes, int n_in,
                              void* d_out, int out_size, void* d_ws, size_t ws_size,
                              hipStream_t stream) {
    const float* x     = (const float*)d_in[0];
    const float* noise = (const float*)d_in[1];
    const float* Wg    = (const float*)d_in[2];
    const float* bg    = (const float*)d_in[3];
    const float* Wn    = (const float*)d_in[4];
    const float* bn    = (const float*)d_in[5];
    const float* W1    = (const float*)d_in[6];
    const float* b1    = (const float*)d_in[7];
    const float* W2    = (const float*)d_in[8];
    const float* b2    = (const float*)d_in[9];
    float* out = (float*)d_out;

    char* ws = (char*)d_ws;
    int*   counts = (int*)ws;                                    // 4 KiB
    int*   slots  = (int*)(ws + 4096);                           // [E][T] 128 KiB
    float* gates  = (float*)(ws + 4096 + NE * T_TOK * 4);        // [E][T] 128 KiB
    unsigned short* xb = (unsigned short*)(ws + 4096 + 2 * NE * T_TOK * 4); // [T][D] bf16, 8 MB
    unsigned short* hh = xb + (size_t)T_TOK * DM;                // [2T][F] bf16, 67 MB
    unsigned short* Wt = hh + (size_t)2 * T_TOK * DF;            // bf16, 67 MB (W1t then W2t)
    unsigned short* eo = Wt + (size_t)NE * DM * DF;              // [2][2T][D] bf16, 34 MB

    hipMemsetAsync(counts, 0, 4096, stream);

    k_router<<<T_TOK / 4, 256, 0, stream>>>(x, noise, Wg, bg, Wn, bn, counts, slots, gates);
    k_xcast<<<T_TOK * DM / 1024, 256, 0, stream>>>(x, xb);

    // W1 [E][D][F] -> Wt [E][F][D]
    k_tr<<<dim3(DF / 64, DM / 64, NE), 256, 0, stream>>>(W1, Wt, DM, DF);
    k_fc1<<<dim3(NE, DF / BN, T_TOK / BM), 256, 0, stream>>>(xb, Wt, b1, counts, slots, hh);

    // W2 [E][F][D] -> Wt [E][D][F]
    k_tr<<<dim3(DM / 64, DF / 64, NE), 256, 0, stream>>>(W2, Wt, DF, DM);
    k_fc2<<<dim3(NE, DM / BN, (T_TOK / BM) * 2), 256, 0, stream>>>(hh, Wt, b2, counts, slots, gates, eo);

    k_comb<<<T_TOK * DM / 1024, 256, 0, stream>>>(eo, out);
}